// Round 4
// baseline (1017.504 us; speedup 1.0000x reference)
//
#include <hip/hip_runtime.h>
#include <stdint.h>
#include <math.h>

typedef __attribute__((ext_vector_type(8))) short short8;
typedef __attribute__((ext_vector_type(4))) float floatx4;
typedef __attribute__((ext_vector_type(16))) float floatx16;

#define B_DIM 2048
#define O_DIM 512
#define H_DIM 1024
#define P_DIM 1024
#define C_DIM 512
#define K_BIG 2560   // H + P + C
#define TAU 0.25f
#define OMT 0.75f

// s_waitcnt imm: vmcnt(n) only; exp=7, lgkm=15 (don't wait)
#define VMCNT(n) ((n) | 0x0F70)
#define MEMFENCE asm volatile("" ::: "memory")

__device__ inline short f2bf(float f) {
  uint32_t u = __float_as_uint(f);
  u += 0x7FFFu + ((u >> 16) & 1u);   // round-to-nearest-even
  return (short)(u >> 16);
}

__device__ inline float sigmoidf_(float x) {
  return 1.0f / (1.0f + __expf(-x));
}

__device__ inline void async_copy16(const void* g, void* l) {
  __builtin_amdgcn_global_load_lds((__attribute__((address_space(1))) void*)g,
                                   (__attribute__((address_space(3))) void*)l,
                                   16, 0, 0);
}

// ---------------------------------------------------------------------------
// Barrier-free split-K 64x64 GEMM core. 4 waves each handle K/4 of the FULL
// 64x64 output tile via 2x2 frags of mfma_f32_32x32x16_bf16 (acc 64 VGPR).
// Each wave owns a private 12KB LDS region = 3 ring buffers x 4KB
// (A 64x16 bf16 = 2KB + B 64x16 = 2KB). Staging via global_load_lds with
// prefetch distance 2; the ONLY sync in the K-loop is the wave's own
// s_waitcnt vmcnt(8). After the loop: cross-wave partial-sum reduction through
// the (dead) staging LDS with a single __syncthreads; wave w returns the
// reduced 32x32 frag it owns (fi=w>>1, fj=w&1).
// LDS chunk layout per buf: A chunk(row,g) = row*2+g (g = 8-col half),
// staged 2 lanes/row (32B contiguous per row -> full-sector L2 reads).
// Frag read: lane reads chunk ((i*32+(lane&31))*2 + (lane>>5)) -> ~2-way banks.
// ---------------------------------------------------------------------------
__device__ inline floatx16 gemm64_splitk(const short* __restrict__ A, int lda,
                                         const short* __restrict__ BT, int ldb,
                                         int Ktot, short* ldsBlk) {
  const int tid = threadIdx.x, lane = tid & 63, w = tid >> 6;
  const int Kw = Ktot >> 2;           // K per wave
  const int nIter = Kw >> 4;          // ksteps of 16
  short* buf = ldsBlk + w * 6144;     // 3 x 2048 shorts

  const int r2 = lane >> 1;
  const int g8 = (lane & 1) * 8;
  const short* gA0 = A + (size_t)r2 * lda + w * Kw + g8;
  const short* gA1 = gA0 + (size_t)32 * lda;
  const short* gB0 = BT + (size_t)r2 * ldb + w * Kw + g8;
  const short* gB1 = gB0 + (size_t)32 * ldb;

  const int m31 = lane & 31, kh = lane >> 5;
  const int aofs = (m31 * 2 + kh) * 8;   // shorts; +i*512 (A), +1024+j*512 (B)

  floatx16 acc[2][2] = {};

  auto stage = [&](int t) {
    short* d = buf + (t % 3) * 2048;
    int ko = t * 16;
    async_copy16(gA0 + ko, d + lane * 8);
    async_copy16(gA1 + ko, d + 512 + lane * 8);
    async_copy16(gB0 + ko, d + 1024 + lane * 8);
    async_copy16(gB1 + ko, d + 1536 + lane * 8);
  };
  auto compute = [&](int t) {
    const short* bc = buf + (t % 3) * 2048;
    short8 a0 = *(const short8*)(bc + aofs);
    short8 a1 = *(const short8*)(bc + 512 + aofs);
    short8 b0 = *(const short8*)(bc + 1024 + aofs);
    short8 b1 = *(const short8*)(bc + 1536 + aofs);
    acc[0][0] = __builtin_amdgcn_mfma_f32_32x32x16_bf16(a0, b0, acc[0][0], 0, 0, 0);
    acc[0][1] = __builtin_amdgcn_mfma_f32_32x32x16_bf16(a0, b1, acc[0][1], 0, 0, 0);
    acc[1][0] = __builtin_amdgcn_mfma_f32_32x32x16_bf16(a1, b0, acc[1][0], 0, 0, 0);
    acc[1][1] = __builtin_amdgcn_mfma_f32_32x32x16_bf16(a1, b1, acc[1][1], 0, 0, 0);
  };

  stage(0);
  stage(1);
  for (int it = 0; it < nIter - 2; ++it) {
    MEMFENCE;
    stage(it + 2);
    __builtin_amdgcn_s_waitcnt(VMCNT(8));   // 8 outstanding = tiles it+1, it+2
    MEMFENCE;
    compute(it);
  }
  MEMFENCE;
  __builtin_amdgcn_s_waitcnt(VMCNT(4));
  MEMFENCE;
  compute(nIter - 2);
  __builtin_amdgcn_s_waitcnt(VMCNT(0));
  MEMFENCE;
  compute(nIter - 1);

  // ---- cross-wave reduction through dead staging LDS (12KB/wave) ----
  union F16 { floatx16 v; floatx4 q[4]; };
  float* red = (float*)ldsBlk;
  float* my = red + w * 3072;          // == wave's own staging region
#pragma unroll
  for (int f = 0; f < 4; ++f) {
    if (f == w) continue;
    int slot = f - (f > w ? 1 : 0);    // 0..2
    F16 u; u.v = acc[f >> 1][f & 1];
#pragma unroll
    for (int q = 0; q < 4; ++q)
      *(floatx4*)&my[slot * 1024 + q * 256 + lane * 4] = u.q[q];
  }
  F16 own; own.v = acc[w >> 1][w & 1];
  __syncthreads();
#pragma unroll
  for (int wp = 0; wp < 4; ++wp) {
    if (wp == w) continue;
    int slot = w - (w > wp ? 1 : 0);
    const float* src = red + wp * 3072 + slot * 1024 + lane * 4;
#pragma unroll
    for (int q = 0; q < 4; ++q) {
      floatx4 t = *(const floatx4*)&src[q * 256];
      own.q[q] += t;
    }
  }
  return own.v;
}

// ---------------- setup kernels ----------------

// WbT [1024 n][2560 k] bf16 = [w_hp ; w_pp(zero diag) ; w_cp]^T
__global__ void k_build_wb(const float* __restrict__ w_hp, const float* __restrict__ w_pp,
                           const float* __restrict__ w_cp, short* __restrict__ WbT) {
  int idx = blockIdx.x * 256 + threadIdx.x;       // 1024*2560
  int n = idx / K_BIG, k = idx - n * K_BIG;
  float v;
  if (k < 1024) v = w_hp[k * P_DIM + n];
  else if (k < 2048) { int r = k - 1024; v = (r == n) ? 0.f : w_pp[r * P_DIM + n]; }
  else v = w_cp[(k - 2048) * P_DIM + n];
  WbT[idx] = f2bf(v);
}

// WpcT [512 n][1024 k]
__global__ void k_build_pc(const float* __restrict__ w_pc, short* __restrict__ WpcT) {
  int idx = blockIdx.x * 256 + threadIdx.x;       // 512*1024
  int n = idx >> 10, k = idx & 1023;
  WpcT[idx] = f2bf(w_pc[k * C_DIM + n]);
}

// WohT [1024 n][512 k]
__global__ void k_build_woh(const float* __restrict__ w_oh, short* __restrict__ WohT) {
  int idx = blockIdx.x * 256 + threadIdx.x;       // 1024*512
  int n = idx >> 9, k = idx & 511;
  WohT[idx] = f2bf(w_oh[k * H_DIM + n]);
}

__global__ void k_build_in(const float* __restrict__ inp, short* __restrict__ inb) {
  int idx = blockIdx.x * 256 + threadIdx.x;       // 2048*512
  inb[idx] = f2bf(inp[idx]);
}

__global__ void k_init(uint32_t* __restrict__ X0, float* __restrict__ p, float* __restrict__ c) {
  int i = blockIdx.x * 256 + threadIdx.x;         // sized for X0 words
  X0[i] = 0x3F003F00u;                            // two bf16 0.5
  if (i < B_DIM * P_DIM) p[i] = 0.f;
  if (i < B_DIM * C_DIM) c[i] = 0.f;
}

// oh = inputs @ w_oh + bias_h   (M=2048,N=1024,K=512) grid 32x16=512
__global__ __launch_bounds__(256, 3) void k_gemm_oh(const short* __restrict__ inb,
                                                    const short* __restrict__ WohT,
                                                    const float* __restrict__ bias_h,
                                                    float* __restrict__ oh) {
  __shared__ short lds[24576];
  int m0 = (blockIdx.x >> 4) * 64;
  int n0 = (((blockIdx.x & 7) * 2) + ((blockIdx.x >> 3) & 1)) * 64;
  floatx16 s = gemm64_splitk(inb + (size_t)m0 * O_DIM, O_DIM,
                             WohT + (size_t)n0 * O_DIM, O_DIM, O_DIM, lds);
  const int lane = threadIdx.x & 63, w = threadIdx.x >> 6;
  int mb = m0 + (w >> 1) * 32 + 4 * (lane >> 5);
  int nn = n0 + (w & 1) * 32 + (lane & 31);
  float bh = bias_h[nn];
#pragma unroll
  for (int r = 0; r < 16; ++r) {
    int m = mb + (r & 3) + 8 * (r >> 2);
    oh[(size_t)m * H_DIM + nn] = s[r] + bh;
  }
}

// ---------------- per-timestep fused kernel ----------------
// blocks [0,512): big GEMM X(2048x2560)@WbT^T -> p/ap update, writes out+Xn(ah,ap)
//   XCD-swizzled: n_tile = (bx&7)*2 + ((bx>>3)&1) keeps each XCD's B-strip L2-hot.
// blocks [512,768): small GEMM ap(2048x1024)@WpcT^T -> c/ac update, writes Xn(ac)
__global__ __launch_bounds__(256, 3) void k_step(const short* __restrict__ Xc,
                                                 short* __restrict__ Xn,
                                                 const short* __restrict__ WbT,
                                                 const short* __restrict__ WpcT,
                                                 const float* __restrict__ bias_p,
                                                 const float* __restrict__ bias_c,
                                                 const float* __restrict__ oh,
                                                 float* __restrict__ p,
                                                 float* __restrict__ c,
                                                 float* __restrict__ out_t,
                                                 float ct) {
  __shared__ short lds[24576];
  const int bx = blockIdx.x;
  const int lane = threadIdx.x & 63, w = threadIdx.x >> 6;

  if (bx < 512) {
    int m0 = (bx >> 4) * 64;
    int n0 = (((bx & 7) * 2) + ((bx >> 3) & 1)) * 64;
    floatx16 s = gemm64_splitk(Xc + (size_t)m0 * K_BIG, K_BIG,
                               WbT + (size_t)n0 * K_BIG, K_BIG, K_BIG, lds);
    int mb = m0 + (w >> 1) * 32 + 4 * (lane >> 5);
    int nn = n0 + (w & 1) * 32 + (lane & 31);
    float bp = bias_p[nn];
#pragma unroll
    for (int r = 0; r < 16; ++r) {
      int m = mb + (r & 3) + 8 * (r >> 2);
      size_t o = (size_t)m * P_DIM + nn;
      float pn = TAU * (s[r] + bp) + OMT * p[o];
      p[o] = pn;
      float ap = sigmoidf_(pn);
      out_t[o] = ap;
      Xn[(size_t)m * K_BIG + H_DIM + nn] = f2bf(ap);
      float ah = sigmoidf_(ct * oh[o]);
      Xn[(size_t)m * K_BIG + nn] = f2bf(ah);
    }
  } else {
    int v = bx - 512;
    int m0 = (v >> 3) * 64;
    int n0 = (v & 7) * 64;
    floatx16 s = gemm64_splitk(Xc + (size_t)m0 * K_BIG + H_DIM, K_BIG,
                               WpcT + (size_t)n0 * P_DIM, P_DIM, P_DIM, lds);
    int mb = m0 + (w >> 1) * 32 + 4 * (lane >> 5);
    int nn = n0 + (w & 1) * 32 + (lane & 31);
    float bc = bias_c[nn];
#pragma unroll
    for (int r = 0; r < 16; ++r) {
      int m = mb + (r & 3) + 8 * (r >> 2);
      size_t o = (size_t)m * C_DIM + nn;
      float cn = TAU * (s[r] + bc) + OMT * c[o];
      c[o] = cn;
      Xn[(size_t)m * K_BIG + H_DIM + P_DIM + nn] = f2bf(sigmoidf_(cn));
    }
  }
}

extern "C" void kernel_launch(void* const* d_in, const int* in_sizes, int n_in,
                              void* d_out, int out_size, void* d_ws, size_t ws_size,
                              hipStream_t stream) {
  const float* inputs = (const float*)d_in[0];
  const float* w_oh   = (const float*)d_in[1];
  const float* w_hp   = (const float*)d_in[2];
  const float* w_pp   = (const float*)d_in[3];
  const float* w_pc   = (const float*)d_in[4];
  const float* w_cp   = (const float*)d_in[5];
  const float* bias_h = (const float*)d_in[6];
  const float* bias_p = (const float*)d_in[7];
  const float* bias_c = (const float*)d_in[8];
  float* out = (float*)d_out;

  char* ws = (char*)d_ws;
  auto alloc = [&](size_t bytes) {
    char* q = ws;
    ws += (bytes + 255) & ~(size_t)255;
    return q;
  };
  short* WbT  = (short*)alloc((size_t)P_DIM * K_BIG * 2);      // 5 MB
  short* WpcT = (short*)alloc((size_t)C_DIM * P_DIM * 2);      // 1 MB
  short* WohT = (short*)alloc((size_t)H_DIM * O_DIM * 2);      // 1 MB
  short* inb  = (short*)alloc((size_t)B_DIM * O_DIM * 2);      // 2 MB
  float* oh   = (float*)alloc((size_t)B_DIM * H_DIM * 4);      // 8 MB
  short* X0   = (short*)alloc((size_t)B_DIM * K_BIG * 2);      // 10.5 MB
  short* X1   = (short*)alloc((size_t)B_DIM * K_BIG * 2);      // 10.5 MB
  float* p    = (float*)alloc((size_t)B_DIM * P_DIM * 4);      // 8 MB
  float* c    = (float*)alloc((size_t)B_DIM * C_DIM * 4);      // 4 MB

  // setup
  k_init<<<dim3((B_DIM * K_BIG / 2) / 256), 256, 0, stream>>>((uint32_t*)X0, p, c);
  k_build_wb<<<dim3((P_DIM * K_BIG) / 256), 256, 0, stream>>>(w_hp, w_pp, w_cp, WbT);
  k_build_pc<<<dim3((C_DIM * P_DIM) / 256), 256, 0, stream>>>(w_pc, WpcT);
  k_build_woh<<<dim3((H_DIM * O_DIM) / 256), 256, 0, stream>>>(w_oh, WohT);
  k_build_in<<<dim3((B_DIM * O_DIM) / 256), 256, 0, stream>>>(inputs, inb);
  k_gemm_oh<<<dim3(512), 256, 0, stream>>>(inb, WohT, bias_h, oh);

  // 12 recurrent steps
  short* Xbuf[2] = {X0, X1};
  for (int t = 1; t <= 12; ++t) {
    float ct = 1.0f - powf(OMT, (float)t);
    k_step<<<dim3(768), 256, 0, stream>>>(Xbuf[(t + 1) & 1], Xbuf[t & 1],
                                          WbT, WpcT, bias_p, bias_c, oh, p, c,
                                          out + (size_t)(t - 1) * B_DIM * P_DIM, ct);
  }
}

// Round 5
// 488.984 us; speedup vs baseline: 2.0809x; 2.0809x over previous
//
#include <hip/hip_runtime.h>
#include <stdint.h>
#include <math.h>

typedef __attribute__((ext_vector_type(8))) short short8;
typedef __attribute__((ext_vector_type(4))) float floatx4;

#define B_DIM 2048
#define O_DIM 512
#define H_DIM 1024
#define P_DIM 1024
#define C_DIM 512
#define K_BIG 2560   // H + P + C
#define TAU 0.25f
#define OMT 0.75f

// s_waitcnt imm (gfx9): vmcnt [3:0]+[15:14], exp [6:4]=7, lgkm [11:8]=15 (no wait)
#define VMCNT(n) (((n) & 15) | (((n) >> 4) << 14) | 0x0F70)
#define MEMFENCE asm volatile("" ::: "memory")

__device__ inline short f2bf(float f) {
  uint32_t u = __float_as_uint(f);
  u += 0x7FFFu + ((u >> 16) & 1u);   // round-to-nearest-even
  return (short)(u >> 16);
}

__device__ inline float sigmoidf_(float x) {
  return 1.0f / (1.0f + __expf(-x));
}

__device__ inline void async_copy16(const void* g, void* l) {
  __builtin_amdgcn_global_load_lds((__attribute__((address_space(1))) void*)g,
                                   (__attribute__((address_space(3))) void*)l,
                                   16, 0, 0);
}

// ---------------------------------------------------------------------------
// 64x64 block tile, BK=64, ring-3 LDS (3 x 16KB), prefetch distance 2,
// ONE barrier per K-iter. 4 waves in 2x2, wave = 32x32 via 2x2 frags of
// mfma_f32_16x16x32_bf16.
//
// Staging: tile row = 128B = 8 chunks of 16B. Thread t covers chunk id
// c = t (rows 0..31) and 256+t (rows 32..63); LDS slot c holds GLOBAL chunk
// (c&7)^(row&7)  -> (a) LDS dests are base + lane*16 (HW constraint),
// (b) each 8-lane group reads one full 128B L2 line, (c) frag reads hit 8
// distinct 16B positions per 8 lanes (bank-spread).
//
// Sync per iter: s_waitcnt vmcnt(4) [tile it landed; tile it+1 in flight]
// -> s_barrier [all waves' tile-it chunks visible AND compute(it-1) done]
// -> stage(it+2) into slot (it-1)%3 -> compute(it).
// ---------------------------------------------------------------------------
__device__ inline void gemm_core64(const short* __restrict__ A, int lda,
                                   const short* __restrict__ BT, int ldb,
                                   int Ktot, short* lds, floatx4 acc[2][2]) {
  const int tid = threadIdx.x, lane = tid & 63, w = tid >> 6;
  const int wm = w >> 1, wn = w & 1;
  const int fm = lane & 15, hi = lane >> 4;

  // staging geometry (chunk id c0 = tid covers rows 0..31; +256 covers 32..63)
  const int r0 = tid >> 3;                       // row 0..31
  const int g0 = (tid & 7) ^ (r0 & 7);           // swizzled global chunk
  const short* gA0 = A + (size_t)r0 * lda + g0 * 8;
  const short* gA1 = A + (size_t)(r0 + 32) * lda + g0 * 8;   // (r0+32)&7 == r0&7
  const short* gB0 = BT + (size_t)r0 * ldb + g0 * 8;
  const short* gB1 = BT + (size_t)(r0 + 32) * ldb + g0 * 8;
  const int dA0 = tid * 8, dA1 = (256 + tid) * 8;
  const int dB0 = 4096 + tid * 8, dB1 = 4096 + (256 + tid) * 8;

  const int nIter = Ktot >> 6;

  auto stage = [&](int t) {
    short* d = lds + (t % 3) * 8192;
    int ko = t * 64;
    async_copy16(gA0 + ko, d + dA0);
    async_copy16(gA1 + ko, d + dA1);
    async_copy16(gB0 + ko, d + dB0);
    async_copy16(gB1 + ko, d + dB1);
  };

  // frag-read LDS offsets (shorts); row&7 == fm&7 for all our rows
  const int sw = fm & 7;

  stage(0);
  stage(1);
  for (int it = 0; it < nIter; ++it) {
    if (it + 1 < nIter) __builtin_amdgcn_s_waitcnt(VMCNT(4));
    else                __builtin_amdgcn_s_waitcnt(VMCNT(0));
    MEMFENCE;
    __builtin_amdgcn_s_barrier();
    MEMFENCE;
    if (it + 2 < nIter) stage(it + 2);
    const short* sb = lds + (it % 3) * 8192;
#pragma unroll
    for (int sl = 0; sl < 2; ++sl) {
      short8 a[2], b[2];
#pragma unroll
      for (int i = 0; i < 2; ++i) {
        int ar = wm * 32 + i * 16 + fm;
        a[i] = *(const short8*)&sb[(ar * 8 + ((sl * 4 + hi) ^ sw)) * 8];
      }
#pragma unroll
      for (int j = 0; j < 2; ++j) {
        int br = wn * 32 + j * 16 + fm;
        b[j] = *(const short8*)&sb[4096 + (br * 8 + ((sl * 4 + hi) ^ sw)) * 8];
      }
#pragma unroll
      for (int i = 0; i < 2; ++i)
#pragma unroll
        for (int j = 0; j < 2; ++j)
          acc[i][j] = __builtin_amdgcn_mfma_f32_16x16x32_bf16(a[i], b[j], acc[i][j], 0, 0, 0);
    }
  }
  MEMFENCE;
}

// ---------------- setup kernels ----------------

// WbT [1024 n][2560 k] bf16 = [w_hp ; w_pp(zero diag) ; w_cp]^T
__global__ void k_build_wb(const float* __restrict__ w_hp, const float* __restrict__ w_pp,
                           const float* __restrict__ w_cp, short* __restrict__ WbT) {
  int idx = blockIdx.x * 256 + threadIdx.x;       // 1024*2560
  int n = idx / K_BIG, k = idx - n * K_BIG;
  float v;
  if (k < 1024) v = w_hp[k * P_DIM + n];
  else if (k < 2048) { int r = k - 1024; v = (r == n) ? 0.f : w_pp[r * P_DIM + n]; }
  else v = w_cp[(k - 2048) * P_DIM + n];
  WbT[idx] = f2bf(v);
}

// WpcT [512 n][1024 k]
__global__ void k_build_pc(const float* __restrict__ w_pc, short* __restrict__ WpcT) {
  int idx = blockIdx.x * 256 + threadIdx.x;       // 512*1024
  int n = idx >> 10, k = idx & 1023;
  WpcT[idx] = f2bf(w_pc[k * C_DIM + n]);
}

// WohT [1024 n][512 k]
__global__ void k_build_woh(const float* __restrict__ w_oh, short* __restrict__ WohT) {
  int idx = blockIdx.x * 256 + threadIdx.x;       // 1024*512
  int n = idx >> 9, k = idx & 511;
  WohT[idx] = f2bf(w_oh[k * H_DIM + n]);
}

__global__ void k_build_in(const float* __restrict__ inp, short* __restrict__ inb) {
  int idx = blockIdx.x * 256 + threadIdx.x;       // 2048*512
  inb[idx] = f2bf(inp[idx]);
}

__global__ void k_init(uint32_t* __restrict__ X0, float* __restrict__ p, float* __restrict__ c) {
  int i = blockIdx.x * 256 + threadIdx.x;         // sized for X0 words
  X0[i] = 0x3F003F00u;                            // two bf16 0.5
  if (i < B_DIM * P_DIM) p[i] = 0.f;
  if (i < B_DIM * C_DIM) c[i] = 0.f;
}

// oh = inputs @ w_oh + bias_h   (M=2048,N=1024,K=512) grid 32x16=512
__global__ __launch_bounds__(256, 3) void k_gemm_oh(const short* __restrict__ inb,
                                                    const short* __restrict__ WohT,
                                                    const float* __restrict__ bias_h,
                                                    float* __restrict__ oh) {
  __shared__ short lds[24576];
  floatx4 acc[2][2] = {};
  int m0 = (blockIdx.x & 31) * 64, n0 = (blockIdx.x >> 5) * 64;
  gemm_core64(inb + (size_t)m0 * O_DIM, O_DIM, WohT + (size_t)n0 * O_DIM, O_DIM,
              O_DIM, lds, acc);
  const int lane = threadIdx.x & 63;
  const int fm = lane & 15, hi = lane >> 4;
  const int w = threadIdx.x >> 6, wm = w >> 1, wn = w & 1;
#pragma unroll
  for (int i = 0; i < 2; ++i)
#pragma unroll
    for (int j = 0; j < 2; ++j)
#pragma unroll
      for (int r = 0; r < 4; ++r) {
        int m = m0 + wm * 32 + i * 16 + hi * 4 + r;
        int n = n0 + wn * 32 + j * 16 + fm;
        oh[(size_t)m * H_DIM + n] = acc[i][j][r] + bias_h[n];
      }
}

// ---------------- per-timestep fused kernel ----------------
// blocks [0,512): big GEMM X(2048x2560)@WbT^T -> p/ap update, writes out+Xn(ah,ap)
// blocks [512,768): small GEMM ap(2048x1024)@WpcT^T -> c/ac update, writes Xn(ac)
__global__ __launch_bounds__(256, 3) void k_step(const short* __restrict__ Xc,
                                                 short* __restrict__ Xn,
                                                 const short* __restrict__ WbT,
                                                 const short* __restrict__ WpcT,
                                                 const float* __restrict__ bias_p,
                                                 const float* __restrict__ bias_c,
                                                 const float* __restrict__ oh,
                                                 float* __restrict__ p,
                                                 float* __restrict__ c,
                                                 float* __restrict__ out_t,
                                                 float ct) {
  __shared__ short lds[24576];
  floatx4 acc[2][2] = {};
  const int lane = threadIdx.x & 63;
  const int fm = lane & 15, hi = lane >> 4;
  const int w = threadIdx.x >> 6, wm = w >> 1, wn = w & 1;
  const int bx = blockIdx.x;

  if (bx < 512) {
    int m0 = (bx & 31) * 64, n0 = (bx >> 5) * 64;
    gemm_core64(Xc + (size_t)m0 * K_BIG, K_BIG, WbT + (size_t)n0 * K_BIG, K_BIG,
                K_BIG, lds, acc);
#pragma unroll
    for (int i = 0; i < 2; ++i)
#pragma unroll
      for (int j = 0; j < 2; ++j)
#pragma unroll
        for (int r = 0; r < 4; ++r) {
          int m = m0 + wm * 32 + i * 16 + hi * 4 + r;
          int n = n0 + wn * 32 + j * 16 + fm;
          size_t o = (size_t)m * P_DIM + n;
          float pn = TAU * (acc[i][j][r] + bias_p[n]) + OMT * p[o];
          p[o] = pn;
          float ap = sigmoidf_(pn);
          out_t[o] = ap;
          Xn[(size_t)m * K_BIG + H_DIM + n] = f2bf(ap);
          float ah = sigmoidf_(ct * oh[o]);
          Xn[(size_t)m * K_BIG + n] = f2bf(ah);
        }
  } else {
    int v = bx - 512;
    int m0 = (v >> 3) * 64, n0 = (v & 7) * 64;
    gemm_core64(Xc + (size_t)m0 * K_BIG + H_DIM, K_BIG, WpcT + (size_t)n0 * P_DIM,
                P_DIM, P_DIM, lds, acc);
#pragma unroll
    for (int i = 0; i < 2; ++i)
#pragma unroll
      for (int j = 0; j < 2; ++j)
#pragma unroll
        for (int r = 0; r < 4; ++r) {
          int m = m0 + wm * 32 + i * 16 + hi * 4 + r;
          int n = n0 + wn * 32 + j * 16 + fm;
          size_t o = (size_t)m * C_DIM + n;
          float cn = TAU * (acc[i][j][r] + bias_c[n]) + OMT * c[o];
          c[o] = cn;
          Xn[(size_t)m * K_BIG + H_DIM + P_DIM + n] = f2bf(sigmoidf_(cn));
        }
  }
}

extern "C" void kernel_launch(void* const* d_in, const int* in_sizes, int n_in,
                              void* d_out, int out_size, void* d_ws, size_t ws_size,
                              hipStream_t stream) {
  const float* inputs = (const float*)d_in[0];
  const float* w_oh   = (const float*)d_in[1];
  const float* w_hp   = (const float*)d_in[2];
  const float* w_pp   = (const float*)d_in[3];
  const float* w_pc   = (const float*)d_in[4];
  const float* w_cp   = (const float*)d_in[5];
  const float* bias_h = (const float*)d_in[6];
  const float* bias_p = (const float*)d_in[7];
  const float* bias_c = (const float*)d_in[8];
  float* out = (float*)d_out;

  char* ws = (char*)d_ws;
  auto alloc = [&](size_t bytes) {
    char* q = ws;
    ws += (bytes + 255) & ~(size_t)255;
    return q;
  };
  short* WbT  = (short*)alloc((size_t)P_DIM * K_BIG * 2);      // 5 MB
  short* WpcT = (short*)alloc((size_t)C_DIM * P_DIM * 2);      // 1 MB
  short* WohT = (short*)alloc((size_t)H_DIM * O_DIM * 2);      // 1 MB
  short* inb  = (short*)alloc((size_t)B_DIM * O_DIM * 2);      // 2 MB
  float* oh   = (float*)alloc((size_t)B_DIM * H_DIM * 4);      // 8 MB
  short* X0   = (short*)alloc((size_t)B_DIM * K_BIG * 2);      // 10.5 MB
  short* X1   = (short*)alloc((size_t)B_DIM * K_BIG * 2);      // 10.5 MB
  float* p    = (float*)alloc((size_t)B_DIM * P_DIM * 4);      // 8 MB
  float* c    = (float*)alloc((size_t)B_DIM * C_DIM * 4);      // 4 MB

  // setup
  k_init<<<dim3((B_DIM * K_BIG / 2) / 256), 256, 0, stream>>>((uint32_t*)X0, p, c);
  k_build_wb<<<dim3((P_DIM * K_BIG) / 256), 256, 0, stream>>>(w_hp, w_pp, w_cp, WbT);
  k_build_pc<<<dim3((C_DIM * P_DIM) / 256), 256, 0, stream>>>(w_pc, WpcT);
  k_build_woh<<<dim3((H_DIM * O_DIM) / 256), 256, 0, stream>>>(w_oh, WohT);
  k_build_in<<<dim3((B_DIM * O_DIM) / 256), 256, 0, stream>>>(inputs, inb);
  k_gemm_oh<<<dim3(512), 256, 0, stream>>>(inb, WohT, bias_h, oh);

  // 12 recurrent steps
  short* Xbuf[2] = {X0, X1};
  for (int t = 1; t <= 12; ++t) {
    float ct = 1.0f - powf(OMT, (float)t);
    k_step<<<dim3(768), 256, 0, stream>>>(Xbuf[(t + 1) & 1], Xbuf[t & 1],
                                          WbT, WpcT, bias_p, bias_c, oh, p, c,
                                          out + (size_t)(t - 1) * B_DIM * P_DIM, ct);
  }
}